// Round 10
// baseline (485.946 us; speedup 1.0000x reference)
//
#include <hip/hip_runtime.h>
#include <math.h>

#define NN 20000
#define NE 320000
#define IN_DIM 16
#define HID 64
#define HEADS 4
#define HD 256          // HEADS*HID
#define OUTW 208        // 16 + 3*64
#define NEG 0.2f

typedef unsigned short u16;
typedef unsigned int u32;
typedef __attribute__((ext_vector_type(8))) short bf16x8;   // MFMA A/B frag
typedef __attribute__((ext_vector_type(8))) unsigned short u16x8;
typedef __attribute__((ext_vector_type(4))) float f32x4;    // MFMA C/D frag

__device__ __forceinline__ float b2f(u16 u) {
  union { u32 i; float f; } c; c.i = ((u32)u) << 16; return c.f;
}
__device__ __forceinline__ u16 f2b(float f) {
  union { float f; u32 i; } c; c.f = f;
  u32 r = (c.i + 0x7FFFu + ((c.i >> 16) & 1u)) >> 16;
  return (u16)r;
}

// ---------------- embed (+ fused edge-count): blocks <5000 embed, rest count
__global__ void k_embed_count(const float* __restrict__ nf, const float* __restrict__ We,
                              const float* __restrict__ be, float* __restrict__ feat,
                              float* __restrict__ out, const int* __restrict__ dst,
                              int* __restrict__ counts) {
  int bid = blockIdx.x;
  const int EB = (NN * 64) / 256;  // 5000
  if (bid < EB) {
    int tid = bid * 256 + threadIdx.x;
    int n = tid >> 6, c = tid & 63;
    float acc = be[c];
#pragma unroll
    for (int k = 0; k < IN_DIM; ++k)
      acc += nf[n * IN_DIM + k] * We[k * HID + c];
    feat[n * HID + c] = acc;
    out[n * OUTW + 16 + c] = acc;
    if (c < IN_DIM) out[n * OUTW + c] = nf[n * IN_DIM + c];
  } else {
    int e = (bid - EB) * 256 + threadIdx.x;
    if (e < NE) atomicAdd(&counts[dst[e]], 1);
  }
}

// single block, 1024 threads, SINGLE-PASS scan: thread t owns nodes
// [t*20, t*20+20) in registers; one wave-scan + one 16-wide wave-sum scan.
// (+ fused cursor zeroing)
__global__ void k_scan(const int* __restrict__ counts, int* __restrict__ rowptr,
                       int* __restrict__ cursor) {
  __shared__ int wsum[16];
  const int PT = 20;                // 1000 active threads * 20 = 20000
  int t = threadIdx.x;
  int lane = t & 63, wid = t >> 6;
  int base = t * PT;
  int c[PT];
  int tot = 0;
  if (t < 1000) {
#pragma unroll
    for (int i = 0; i < PT; ++i) {
      int v = counts[base + i];
      cursor[base + i] = 0;
      tot += v;
      c[i] = tot;                   // inclusive thread-local prefix
    }
  }
  // wave-level scan of per-thread totals
  int x = tot;
#pragma unroll
  for (int d = 1; d < 64; d <<= 1) {
    int y = __shfl_up(x, d);
    if (lane >= d) x += y;
  }
  int lexcl = x - tot;              // exclusive within wave
  if (lane == 63) wsum[wid] = x;
  __syncthreads();
  if (wid == 0) {
    int wv = (lane < 16) ? wsum[lane] : 0;
#pragma unroll
    for (int d = 1; d < 16; d <<= 1) {
      int y = __shfl_up(wv, d);
      if (lane >= d) wv += y;
    }
    if (lane < 16) wsum[lane] = wv; // inclusive wave sums
  }
  __syncthreads();
  int woff = (wid == 0) ? 0 : wsum[wid - 1];
  int offset = woff + lexcl;
  if (t == 0) rowptr[0] = 0;
  if (t < 1000) {
#pragma unroll
    for (int i = 0; i < PT; ++i) rowptr[base + i + 1] = offset + c[i];
  }
}

// scatter: sd[pos] = {src,dst} as ONE int2 (halves scattered-store instrs);
// pos_of (edge -> CSR slot) for the scatter-style permute.
__global__ void k_scatter(const int* __restrict__ dst, const int* __restrict__ src,
                          const int* __restrict__ rowptr, int* __restrict__ cursor,
                          int2* __restrict__ sd, int* __restrict__ pos_of) {
  int e = blockIdx.x * blockDim.x + threadIdx.x;
  if (e >= NE) return;
  int d = dst[e];
  int pos = rowptr[d] + atomicAdd(&cursor[d], 1);
  sd[pos] = make_int2(src[e], d);
  pos_of[e] = pos;
}

// ---------------- SCATTER-permute+convert edge_feat into CSR slot order (bf16).
// Streams ef coalesced (no gather-latency chain), scatter-writes 128B bf16 rows.
// Fused: transpose+bf16 of W_fij for BOTH layers (tiny tail blocks).
__global__ void k_permute_prepw(const float* __restrict__ ef, const int* __restrict__ pos_of,
                                u16* __restrict__ efbp, const float* __restrict__ Wf,
                                u16* __restrict__ Wt0, u16* __restrict__ Wt1) {
  int bid = blockIdx.x;
  const int PB = (NE * 16) / 256;  // 20000
  if (bid < PB) {
    int t = bid * 256 + threadIdx.x;
    int e = t >> 4, c = (t & 15) * 4;
    int slot = pos_of[e];                             // coalesced/broadcast read
    float4 v = *reinterpret_cast<const float4*>(&ef[(size_t)e * HID + c]);  // streaming
    ushort4 o;
    o.x = f2b(v.x); o.y = f2b(v.y); o.z = f2b(v.z); o.w = f2b(v.w);
    *reinterpret_cast<ushort4*>(&efbp[(size_t)slot * HID + c]) = o;        // scatter row
  } else {
    int r = (bid - PB) * 256 + threadIdx.x;   // 0..32767 over 128 blocks
    int Lw = r >> 14;                          // 16384 entries per layer
    int idx = r & 16383;
    int nn2 = idx >> 6, kk2 = idx & 63;
    u16* WtL = Lw ? Wt1 : Wt0;
    WtL[nn2 * HID + kk2] = f2b(Wf[(size_t)Lw * HID * HD + kk2 * HD + nn2]);
  }
}

// ---------------- node projections: fni (+b_att folded), fnj, hn -> bf16.
// 16 nodes/block (halves per-element weight re-read traffic vs 8/block).
__global__ __launch_bounds__(256) void k_nodeproj(
    const float* __restrict__ feat, const float* __restrict__ Wni,
    const float* __restrict__ Wnj, const float* __restrict__ Wnd,
    const float* __restrict__ batt, u16* __restrict__ fni,
    u16* __restrict__ fnj, u16* __restrict__ hn) {
  __shared__ float hs[16 * HID];
  int n0 = blockIdx.x * 16;
  int c = threadIdx.x;
  for (int i = threadIdx.x; i < 16 * HID; i += 256)
    hs[i] = feat[(size_t)(n0 + (i >> 6)) * HID + (i & 63)];
  __syncthreads();
  float aI[16] = {0}, aJ[16] = {0}, aN[16] = {0};
  for (int k = 0; k < HID; ++k) {
    float wi = Wni[k * HD + c], wj = Wnj[k * HD + c], wn = Wnd[k * HD + c];
#pragma unroll
    for (int t = 0; t < 16; ++t) {
      float x = hs[t * HID + k];
      aI[t] += x * wi; aJ[t] += x * wj; aN[t] += x * wn;
    }
  }
  float b = batt[c];
#pragma unroll
  for (int t = 0; t < 16; ++t) {
    int n = n0 + t;
    fni[(size_t)n * HD + c] = f2b(aI[t] + b);
    fnj[(size_t)n * HD + c] = f2b(aJ[t]);
    hn[(size_t)n * HD + c]  = f2b(aN[t]);
  }
}

// ---------------- edge logits via MFMA over CSR slots, 2-tile ILP.
// R7 structure: XCD-aware block swizzle + ADJACENT-pair tiles; ushort4
// gathers; conflict-free LDS commit [p*4+q][4*n]; sd int2 index loads
// (one 8B load per edge instead of two 4B). elog[h*NE + slot].
__global__ __launch_bounds__(256) void k_edgelogits(
    const u16* __restrict__ efbp, const int2* __restrict__ sd,
    const u16* __restrict__ fni, const u16* __restrict__ fnj,
    const u16* __restrict__ Wt, const float* __restrict__ attnL,
    float* __restrict__ elog) {
  __shared__ float gb[HEADS][16][68];   // per-wave slice, +4 pad
  int h = threadIdx.x >> 6;            // wave = head
  int l = threadIdx.x & 63;
  int q = l >> 4;                      // quad
  int n = l & 15;
  bf16x8 bfr[4][2];
#pragma unroll
  for (int nt = 0; nt < 4; ++nt)
#pragma unroll
    for (int kk = 0; kk < 2; ++kk)
      bfr[nt][kk] = *reinterpret_cast<const bf16x8*>(
          &Wt[(h * 64 + nt * 16 + n) * HID + kk * 32 + q * 8]);
  float at[4];
#pragma unroll
  for (int nt = 0; nt < 4; ++nt) at[nt] = attnL[h * 64 + nt * 16 + n];

#define COMMIT(av, bv)                                                \
  {                                                                   \
    _Pragma("unroll")                                                 \
    for (int p = 0; p < 4; ++p) {                                     \
      float4 g;                                                       \
      g.x = b2f(av[p].x) + b2f(bv[p].x);                              \
      g.y = b2f(av[p].y) + b2f(bv[p].y);                              \
      g.z = b2f(av[p].z) + b2f(bv[p].z);                              \
      g.w = b2f(av[p].w) + b2f(bv[p].w);                              \
      *reinterpret_cast<float4*>(&gb[h][p * 4 + q][4 * n]) = g;       \
    }                                                                 \
  }

#define TILEMMA(aa0, aa1, ibase)                                                  \
  {                                                                               \
    float sumr[4] = {0.f, 0.f, 0.f, 0.f};                                         \
    _Pragma("unroll")                                                             \
    for (int nt = 0; nt < 4; ++nt) {                                              \
      f32x4 acc = {0.f, 0.f, 0.f, 0.f};                                           \
      acc = __builtin_amdgcn_mfma_f32_16x16x32_bf16(aa0, bfr[nt][0], acc, 0, 0, 0); \
      acc = __builtin_amdgcn_mfma_f32_16x16x32_bf16(aa1, bfr[nt][1], acc, 0, 0, 0); \
      _Pragma("unroll")                                                           \
      for (int r = 0; r < 4; ++r) {                                               \
        float v = acc[r] + gb[h][q * 4 + r][nt * 16 + n];                         \
        v = v > 0.f ? v : NEG * v;                                                \
        sumr[r] += v * at[nt];                                                    \
      }                                                                           \
    }                                                                             \
    _Pragma("unroll")                                                             \
    for (int r = 0; r < 4; ++r) {                                                 \
      float v = sumr[r];                                                          \
      v += __shfl_xor(v, 1);                                                      \
      v += __shfl_xor(v, 2);                                                      \
      v += __shfl_xor(v, 4);                                                      \
      v += __shfl_xor(v, 8);                                                      \
      sumr[r] = v;                                                                \
    }                                                                             \
    if (n == 0) {                                                                 \
      float4 o_;                                                                  \
      o_.x = sumr[0]; o_.y = sumr[1]; o_.z = sumr[2]; o_.w = sumr[3];             \
      *reinterpret_cast<float4*>(&elog[(size_t)h * NE + (ibase) + q * 4]) = o_;   \
    }                                                                             \
  }

  const int NT2 = NE / 32;  // 10000 pair-groups
  const int G = gridDim.x;  // 2048 (multiple of 8)
  int swz = (blockIdx.x & 7) * (G >> 3) + (blockIdx.x >> 3);  // XCD-contiguous
  for (int pg = swz; pg < NT2; pg += G) {
    int i0 = pg * 32;        // tiles 2pg and 2pg+1: adjacent 16-edge groups
    int i1 = i0 + 16;
    // ---- issue ALL gathers for both tiles (2x memory-level parallelism)
    bf16x8 a00 = *reinterpret_cast<const bf16x8*>(&efbp[(size_t)(i0 + n) * HID + q * 8]);
    bf16x8 a01 = *reinterpret_cast<const bf16x8*>(&efbp[(size_t)(i0 + n) * HID + 32 + q * 8]);
    ushort4 av0[4], bv0[4];
#pragma unroll
    for (int p = 0; p < 4; ++p) {
      int2 x = sd[i0 + p * 4 + q];
      av0[p] = *reinterpret_cast<const ushort4*>(&fni[(size_t)x.x * HD + h * 64 + 4 * n]);
      bv0[p] = *reinterpret_cast<const ushort4*>(&fnj[(size_t)x.y * HD + h * 64 + 4 * n]);
    }
    bf16x8 a10 = *reinterpret_cast<const bf16x8*>(&efbp[(size_t)(i1 + n) * HID + q * 8]);
    bf16x8 a11 = *reinterpret_cast<const bf16x8*>(&efbp[(size_t)(i1 + n) * HID + 32 + q * 8]);
    ushort4 av1[4], bv1[4];
#pragma unroll
    for (int p = 0; p < 4; ++p) {
      int2 x = sd[i1 + p * 4 + q];
      av1[p] = *reinterpret_cast<const ushort4*>(&fni[(size_t)x.x * HD + h * 64 + 4 * n]);
      bv1[p] = *reinterpret_cast<const ushort4*>(&fnj[(size_t)x.y * HD + h * 64 + 4 * n]);
    }
    // ---- tile 0: commit to wave-private LDS, MFMA, epilogue
    COMMIT(av0, bv0);
    TILEMMA(a00, a01, i0);
    // ---- tile 1 (same LDS slice, wave-private reuse)
    COMMIT(av1, bv1);
    TILEMMA(a10, a11, i1);
  }
#undef COMMIT
#undef TILEMMA
}

// ---------------- FUSED aggregation + MLP + residual (R9 structure).
// Phase 1 (per wave, 4 consecutive nodes): softmax-weighted aggregation into
// LDS (16 nodes x 256 f32). Phase 2: out = aggLDS @ W_mlp + b + feat.
__global__ __launch_bounds__(256) void k_agg_mlp(
    const int* __restrict__ rowptr, const int2* __restrict__ sd,
    const float* __restrict__ elog, const u16* __restrict__ hn,
    const float* __restrict__ Wm, const float* __restrict__ bm,
    float* __restrict__ feat, float* __restrict__ out, int outoff) {
  __shared__ float as_[16 * HD];     // 16 KB: 16 nodes x 256
  int j = threadIdx.x & 63;
  int wid = threadIdx.x >> 6;        // 0..3
  int half = j >> 5;                 // which edge of a pair this lane serves
  int lo = j & 31;                   // col-chunk: cols 8*lo..8*lo+7
  int hA = (j >> 3) & 3;             // head of this lane's columns
  int u = (j & 7) + 8 * half;        // strided index 0..15 within head group
  const float* er = elog + (size_t)hA * NE;
  int n0 = blockIdx.x * 16;
  // ---- phase 1: aggregate 4 consecutive nodes per wave into LDS
#pragma unroll 1
  for (int t4 = 0; t4 < 4; ++t4) {
    int n = n0 + wid * 4 + t4;
    int s0 = rowptr[n], s1 = rowptr[n + 1];
    // fused m/z: strided over the row, reduce within 16-lane head group
    float m = -1e30f;
    for (int i = s0 + u; i < s1; i += 16) m = fmaxf(m, er[i]);
    m = fmaxf(m, __shfl_xor(m, 1));
    m = fmaxf(m, __shfl_xor(m, 2));
    m = fmaxf(m, __shfl_xor(m, 4));
    m = fmaxf(m, __shfl_xor(m, 32));
    float z = 0.f;
    for (int i = s0 + u; i < s1; i += 16) z += __expf(er[i] - m);
    z += __shfl_xor(z, 1);
    z += __shfl_xor(z, 2);
    z += __shfl_xor(z, 4);
    z += __shfl_xor(z, 32);
    float invz = (z > 0.f) ? 1.0f / z : 0.f;
    // weighted aggregation: 8 floats (one 16B col-chunk) per lane
    float a8[8] = {0.f, 0.f, 0.f, 0.f, 0.f, 0.f, 0.f, 0.f};
    int i = s0;
    for (; i + 8 <= s1; i += 8) {
      int sv[8]; float wv[8];
#pragma unroll
      for (int t = 0; t < 8; ++t) sv[t] = sd[i + t].x;
#pragma unroll
      for (int t = 0; t < 8; ++t) wv[t] = __expf(er[i + t] - m) * invz;
      u16x8 vv[4];
#pragma unroll
      for (int g = 0; g < 4; ++g)
        vv[g] = *reinterpret_cast<const u16x8*>(&hn[(size_t)sv[2 * g + half] * HD + 8 * lo]);
#pragma unroll
      for (int g = 0; g < 4; ++g) {
        float w = wv[2 * g + half];
#pragma unroll
        for (int e = 0; e < 8; ++e) a8[e] += b2f(vv[g][e]) * w;
      }
    }
    // pair tail: lanes half=0/1 take edges i/i+1 (merged by final xor-32)
    for (; i + 2 <= s1; i += 2) {
      int s = sd[i + half].x;
      float w = __expf(er[i + half] - m) * invz;
      u16x8 v = *reinterpret_cast<const u16x8*>(&hn[(size_t)s * HD + 8 * lo]);
#pragma unroll
      for (int e = 0; e < 8; ++e) a8[e] += b2f(v[e]) * w;
    }
    if (i < s1) {   // final odd edge
      int s = sd[i].x;
      float w = half ? 0.f : (__expf(er[i] - m) * invz);
      u16x8 v = *reinterpret_cast<const u16x8*>(&hn[(size_t)s * HD + 8 * lo]);
#pragma unroll
      for (int e = 0; e < 8; ++e) a8[e] += b2f(v[e]) * w;
    }
    // merge the two edge-halves (lanes j and j^32 own the same columns)
#pragma unroll
    for (int e = 0; e < 8; ++e) a8[e] += __shfl_xor(a8[e], 32);
    if (j < 32) {
      int row = wid * 4 + t4;
      float4 o0, o1;
      o0.x = a8[0]; o0.y = a8[1]; o0.z = a8[2]; o0.w = a8[3];
      o1.x = a8[4]; o1.y = a8[5]; o1.z = a8[6]; o1.w = a8[7];
      *reinterpret_cast<float4*>(&as_[row * HD + 8 * lo]) = o0;
      *reinterpret_cast<float4*>(&as_[row * HD + 8 * lo + 4]) = o1;
    }
  }
  __syncthreads();
  // ---- phase 2: MLP + residual from LDS
  int c = threadIdx.x & 63;
  int g = threadIdx.x >> 6;
  float acc[4] = {0.f, 0.f, 0.f, 0.f};
  for (int k = 0; k < HD; ++k) {
    float wv = Wm[k * HID + c];
#pragma unroll
    for (int t = 0; t < 4; ++t)
      acc[t] += as_[(g * 4 + t) * HD + k] * wv;
  }
  float b = bm[c];
#pragma unroll
  for (int t = 0; t < 4; ++t) {
    int n = n0 + g * 4 + t;
    float v = acc[t] + b + feat[n * HID + c];
    feat[n * HID + c] = v;
    out[n * OUTW + outoff + c] = v;
  }
}

extern "C" void kernel_launch(void* const* d_in, const int* in_sizes, int n_in,
                              void* d_out, int out_size, void* d_ws, size_t ws_size,
                              hipStream_t stream) {
  const float* node_feat = (const float*)d_in[0];
  const float* edge_feat = (const float*)d_in[1];
  const int*   src       = (const int*)d_in[2];
  const int*   dst       = (const int*)d_in[3];
  const float* W_embed   = (const float*)d_in[4];
  const float* b_embed   = (const float*)d_in[5];
  const float* W_ni      = (const float*)d_in[6];
  const float* W_nj      = (const float*)d_in[7];
  const float* W_fij     = (const float*)d_in[8];
  const float* b_att     = (const float*)d_in[9];
  const float* attn      = (const float*)d_in[10];
  const float* W_node    = (const float*)d_in[11];
  const float* W_mlp     = (const float*)d_in[12];
  const float* b_mlp     = (const float*)d_in[13];
  float* out = (float*)d_out;

  // workspace layout
  float* ws   = (float*)d_ws;
  float* feat = ws;                                   // NN*HID f32
  u16*  fni   = (u16*)(feat + (size_t)NN * HID);      // NN*HD bf16
  u16*  fnj   = fni + (size_t)NN * HD;                // NN*HD bf16
  u16*  hn    = fnj + (size_t)NN * HD;                // NN*HD bf16
  u16*  efbp  = hn + (size_t)NN * HD;                 // NE*HID bf16 (CSR slot order)
  u16*  Wt0   = efbp + (size_t)NE * HID;              // HD*HID bf16
  u16*  Wt1   = Wt0 + (size_t)HD * HID;               // HD*HID bf16
  float* elog = (float*)(Wt1 + (size_t)HD * HID);     // HEADS*NE f32 (head-major)
  int* counts = (int*)(elog + (size_t)NE * HEADS);    // NN
  int* rowptr = counts + NN;                          // NN+1
  int* cursor = rowptr + NN + 1;                      // NN
  int2* sd    = (int2*)(cursor + NN);                 // NE int2 {src,dst}
  int* pos_of = (int*)(sd + NE);                      // NE

  hipMemsetAsync(counts, 0, sizeof(int) * NN, stream);

  k_embed_count<<<(NN * 64) / 256 + NE / 256, 256, 0, stream>>>(
      node_feat, W_embed, b_embed, feat, out, dst, counts);
  k_scan<<<1, 1024, 0, stream>>>(counts, rowptr, cursor);
  k_scatter<<<NE / 256, 256, 0, stream>>>(dst, src, rowptr, cursor, sd, pos_of);
  k_permute_prepw<<<(NE * 16) / 256 + 128, 256, 0, stream>>>(
      edge_feat, pos_of, efbp, W_fij, Wt0, Wt1);

  for (int L = 0; L < 2; ++L) {
    const float* WniL = W_ni + (size_t)L * HID * HD;
    const float* WnjL = W_nj + (size_t)L * HID * HD;
    const float* WndL = W_node + (size_t)L * HID * HD;
    const float* battL = b_att + (size_t)L * HD;
    const float* attnL = attn + (size_t)L * HEADS * HID;
    const float* WmL  = W_mlp + (size_t)L * HD * HID;
    const float* bmL  = b_mlp + (size_t)L * HID;
    u16* WtL = L ? Wt1 : Wt0;

    k_nodeproj<<<NN / 16, 256, 0, stream>>>(feat, WniL, WnjL, WndL, battL, fni, fnj, hn);
    k_edgelogits<<<2048, 256, 0, stream>>>(efbp, sd, fni, fnj, WtL, attnL, elog);
    k_agg_mlp<<<NN / 16, 256, 0, stream>>>(rowptr, sd, elog, hn, WmL, bmL,
                                           feat, out, 80 + L * 64);
  }
}

// Round 11
// 467.124 us; speedup vs baseline: 1.0403x; 1.0403x over previous
//
#include <hip/hip_runtime.h>
#include <math.h>

#define NN 20000
#define NE 320000
#define IN_DIM 16
#define HID 64
#define HEADS 4
#define HD 256          // HEADS*HID
#define OUTW 208        // 16 + 3*64
#define NEG 0.2f

typedef unsigned short u16;
typedef unsigned int u32;
typedef __attribute__((ext_vector_type(8))) short bf16x8;   // MFMA A/B frag
typedef __attribute__((ext_vector_type(8))) unsigned short u16x8;
typedef __attribute__((ext_vector_type(4))) float f32x4;    // MFMA C/D frag

__device__ __forceinline__ float b2f(u16 u) {
  union { u32 i; float f; } c; c.i = ((u32)u) << 16; return c.f;
}
__device__ __forceinline__ u16 f2b(float f) {
  union { float f; u32 i; } c; c.f = f;
  u32 r = (c.i + 0x7FFFu + ((c.i >> 16) & 1u)) >> 16;
  return (u16)r;
}

// ---------------- FUSED embed + L0 node projections (+ edge-count tail).
// Blocks < 1250: 16 nodes each — embed into LDS, write feat/out, then project
// to fni (+b_att), fnj, hn with the proven 8-node/24-acc loop (x2 halves).
// Blocks >= 1250: edge-count for CSR build.
__global__ __launch_bounds__(256) void k_embed_count_proj(
    const float* __restrict__ nf, const float* __restrict__ We,
    const float* __restrict__ be, const float* __restrict__ Wni,
    const float* __restrict__ Wnj, const float* __restrict__ Wnd,
    const float* __restrict__ batt, float* __restrict__ feat,
    float* __restrict__ out, const int* __restrict__ dst,
    int* __restrict__ counts, u16* __restrict__ fni,
    u16* __restrict__ fnj, u16* __restrict__ hn) {
  int bid = blockIdx.x;
  const int EB = NN / 16;  // 1250
  if (bid < EB) {
    __shared__ float fs[16 * HID];   // 4 KB
    int n0 = bid * 16;
    int c = threadIdx.x & 63;
    int g = threadIdx.x >> 6;        // 0..3, each group embeds 4 nodes
#pragma unroll
    for (int t = 0; t < 4; ++t) {
      int r = g * 4 + t;
      int n = n0 + r;
      float acc = be[c];
#pragma unroll
      for (int k = 0; k < IN_DIM; ++k)
        acc += nf[n * IN_DIM + k] * We[k * HID + c];
      fs[r * HID + c] = acc;
      feat[(size_t)n * HID + c] = acc;
      out[(size_t)n * OUTW + 16 + c] = acc;
      if (c < IN_DIM) out[(size_t)n * OUTW + c] = nf[n * IN_DIM + c];
    }
    __syncthreads();
    int cc = threadIdx.x;            // 0..255: output column in HD
    float b = batt[cc];
#pragma unroll 1
    for (int h8 = 0; h8 < 2; ++h8) {
      float aI[8] = {0}, aJ[8] = {0}, aN[8] = {0};
      for (int k = 0; k < HID; ++k) {
        float wi = Wni[k * HD + cc], wj = Wnj[k * HD + cc], wn = Wnd[k * HD + cc];
#pragma unroll
        for (int t = 0; t < 8; ++t) {
          float x = fs[(h8 * 8 + t) * HID + k];
          aI[t] += x * wi; aJ[t] += x * wj; aN[t] += x * wn;
        }
      }
#pragma unroll
      for (int t = 0; t < 8; ++t) {
        int n = n0 + h8 * 8 + t;
        fni[(size_t)n * HD + cc] = f2b(aI[t] + b);
        fnj[(size_t)n * HD + cc] = f2b(aJ[t]);
        hn[(size_t)n * HD + cc]  = f2b(aN[t]);
      }
    }
  } else {
    int e = (bid - EB) * 256 + threadIdx.x;
    if (e < NE) atomicAdd(&counts[dst[e]], 1);
  }
}

// single block, 1024 threads, SINGLE-PASS scan: thread t owns nodes
// [t*20, t*20+20) in registers; one wave-scan + one 16-wide wave-sum scan.
// (+ fused cursor zeroing)
__global__ void k_scan(const int* __restrict__ counts, int* __restrict__ rowptr,
                       int* __restrict__ cursor) {
  __shared__ int wsum[16];
  const int PT = 20;                // 1000 active threads * 20 = 20000
  int t = threadIdx.x;
  int lane = t & 63, wid = t >> 6;
  int base = t * PT;
  int c[PT];
  int tot = 0;
  if (t < 1000) {
#pragma unroll
    for (int i = 0; i < PT; ++i) {
      int v = counts[base + i];
      cursor[base + i] = 0;
      tot += v;
      c[i] = tot;                   // inclusive thread-local prefix
    }
  }
  // wave-level scan of per-thread totals
  int x = tot;
#pragma unroll
  for (int d = 1; d < 64; d <<= 1) {
    int y = __shfl_up(x, d);
    if (lane >= d) x += y;
  }
  int lexcl = x - tot;              // exclusive within wave
  if (lane == 63) wsum[wid] = x;
  __syncthreads();
  if (wid == 0) {
    int wv = (lane < 16) ? wsum[lane] : 0;
#pragma unroll
    for (int d = 1; d < 16; d <<= 1) {
      int y = __shfl_up(wv, d);
      if (lane >= d) wv += y;
    }
    if (lane < 16) wsum[lane] = wv; // inclusive wave sums
  }
  __syncthreads();
  int woff = (wid == 0) ? 0 : wsum[wid - 1];
  int offset = woff + lexcl;
  if (t == 0) rowptr[0] = 0;
  if (t < 1000) {
#pragma unroll
    for (int i = 0; i < PT; ++i) rowptr[base + i + 1] = offset + c[i];
  }
}

// scatter: src/dst permuted into CSR order + pos_of (edge -> CSR slot)
__global__ void k_scatter(const int* __restrict__ dst, const int* __restrict__ src,
                          const int* __restrict__ rowptr, int* __restrict__ cursor,
                          int* __restrict__ srcp, int* __restrict__ dstp,
                          int* __restrict__ pos_of) {
  int e = blockIdx.x * blockDim.x + threadIdx.x;
  if (e >= NE) return;
  int d = dst[e];
  int pos = rowptr[d] + atomicAdd(&cursor[d], 1);
  srcp[pos] = src[e];
  dstp[pos] = d;
  pos_of[e] = pos;
}

// ---------------- SCATTER-permute+convert edge_feat into CSR slot order (bf16).
// Streams ef coalesced (no gather-latency chain), scatter-writes 128B bf16 rows.
// Fused: transpose+bf16 of W_fij for BOTH layers (tiny tail blocks).
__global__ void k_permute_prepw(const float* __restrict__ ef, const int* __restrict__ pos_of,
                                u16* __restrict__ efbp, const float* __restrict__ Wf,
                                u16* __restrict__ Wt0, u16* __restrict__ Wt1) {
  int bid = blockIdx.x;
  const int PB = (NE * 16) / 256;  // 20000
  if (bid < PB) {
    int t = bid * 256 + threadIdx.x;
    int e = t >> 4, c = (t & 15) * 4;
    int slot = pos_of[e];                             // coalesced/broadcast read
    float4 v = *reinterpret_cast<const float4*>(&ef[(size_t)e * HID + c]);  // streaming
    ushort4 o;
    o.x = f2b(v.x); o.y = f2b(v.y); o.z = f2b(v.z); o.w = f2b(v.w);
    *reinterpret_cast<ushort4*>(&efbp[(size_t)slot * HID + c]) = o;        // scatter row
  } else {
    int r = (bid - PB) * 256 + threadIdx.x;   // 0..32767 over 128 blocks
    int Lw = r >> 14;                          // 16384 entries per layer
    int idx = r & 16383;
    int nn2 = idx >> 6, kk2 = idx & 63;
    u16* WtL = Lw ? Wt1 : Wt0;
    WtL[nn2 * HID + kk2] = f2b(Wf[(size_t)Lw * HID * HD + kk2 * HD + nn2]);
  }
}

// ---------------- edge logits via MFMA over CSR slots, 2-tile ILP.
// R7 structure: XCD-aware block swizzle + ADJACENT-pair tiles; ushort4
// gathers; conflict-free LDS commit [p*4+q][4*n]. elog[h*NE + slot].
__global__ __launch_bounds__(256) void k_edgelogits(
    const u16* __restrict__ efbp, const int* __restrict__ srcp,
    const int* __restrict__ dstp, const u16* __restrict__ fni,
    const u16* __restrict__ fnj, const u16* __restrict__ Wt,
    const float* __restrict__ attnL, float* __restrict__ elog) {
  __shared__ float gb[HEADS][16][68];   // per-wave slice, +4 pad
  int h = threadIdx.x >> 6;            // wave = head
  int l = threadIdx.x & 63;
  int q = l >> 4;                      // quad
  int n = l & 15;
  bf16x8 bfr[4][2];
#pragma unroll
  for (int nt = 0; nt < 4; ++nt)
#pragma unroll
    for (int kk = 0; kk < 2; ++kk)
      bfr[nt][kk] = *reinterpret_cast<const bf16x8*>(
          &Wt[(h * 64 + nt * 16 + n) * HID + kk * 32 + q * 8]);
  float at[4];
#pragma unroll
  for (int nt = 0; nt < 4; ++nt) at[nt] = attnL[h * 64 + nt * 16 + n];

#define COMMIT(av, bv)                                                \
  {                                                                   \
    _Pragma("unroll")                                                 \
    for (int p = 0; p < 4; ++p) {                                     \
      float4 g;                                                       \
      g.x = b2f(av[p].x) + b2f(bv[p].x);                              \
      g.y = b2f(av[p].y) + b2f(bv[p].y);                              \
      g.z = b2f(av[p].z) + b2f(bv[p].z);                              \
      g.w = b2f(av[p].w) + b2f(bv[p].w);                              \
      *reinterpret_cast<float4*>(&gb[h][p * 4 + q][4 * n]) = g;       \
    }                                                                 \
  }

#define TILEMMA(aa0, aa1, ibase)                                                  \
  {                                                                               \
    float sumr[4] = {0.f, 0.f, 0.f, 0.f};                                         \
    _Pragma("unroll")                                                             \
    for (int nt = 0; nt < 4; ++nt) {                                              \
      f32x4 acc = {0.f, 0.f, 0.f, 0.f};                                           \
      acc = __builtin_amdgcn_mfma_f32_16x16x32_bf16(aa0, bfr[nt][0], acc, 0, 0, 0); \
      acc = __builtin_amdgcn_mfma_f32_16x16x32_bf16(aa1, bfr[nt][1], acc, 0, 0, 0); \
      _Pragma("unroll")                                                           \
      for (int r = 0; r < 4; ++r) {                                               \
        float v = acc[r] + gb[h][q * 4 + r][nt * 16 + n];                         \
        v = v > 0.f ? v : NEG * v;                                                \
        sumr[r] += v * at[nt];                                                    \
      }                                                                           \
    }                                                                             \
    _Pragma("unroll")                                                             \
    for (int r = 0; r < 4; ++r) {                                                 \
      float v = sumr[r];                                                          \
      v += __shfl_xor(v, 1);                                                      \
      v += __shfl_xor(v, 2);                                                      \
      v += __shfl_xor(v, 4);                                                      \
      v += __shfl_xor(v, 8);                                                      \
      sumr[r] = v;                                                                \
    }                                                                             \
    if (n == 0) {                                                                 \
      float4 o_;                                                                  \
      o_.x = sumr[0]; o_.y = sumr[1]; o_.z = sumr[2]; o_.w = sumr[3];             \
      *reinterpret_cast<float4*>(&elog[(size_t)h * NE + (ibase) + q * 4]) = o_;   \
    }                                                                             \
  }

  const int NT2 = NE / 32;  // 10000 pair-groups
  const int G = gridDim.x;  // 2048 (multiple of 8)
  int swz = (blockIdx.x & 7) * (G >> 3) + (blockIdx.x >> 3);  // XCD-contiguous
  for (int pg = swz; pg < NT2; pg += G) {
    int i0 = pg * 32;        // tiles 2pg and 2pg+1: adjacent 16-edge groups
    int i1 = i0 + 16;
    // ---- issue ALL gathers for both tiles (2x memory-level parallelism)
    bf16x8 a00 = *reinterpret_cast<const bf16x8*>(&efbp[(size_t)(i0 + n) * HID + q * 8]);
    bf16x8 a01 = *reinterpret_cast<const bf16x8*>(&efbp[(size_t)(i0 + n) * HID + 32 + q * 8]);
    ushort4 av0[4], bv0[4];
#pragma unroll
    for (int p = 0; p < 4; ++p) {
      int i = i0 + p * 4 + q;
      int s = srcp[i], d = dstp[i];
      av0[p] = *reinterpret_cast<const ushort4*>(&fni[(size_t)s * HD + h * 64 + 4 * n]);
      bv0[p] = *reinterpret_cast<const ushort4*>(&fnj[(size_t)d * HD + h * 64 + 4 * n]);
    }
    bf16x8 a10 = *reinterpret_cast<const bf16x8*>(&efbp[(size_t)(i1 + n) * HID + q * 8]);
    bf16x8 a11 = *reinterpret_cast<const bf16x8*>(&efbp[(size_t)(i1 + n) * HID + 32 + q * 8]);
    ushort4 av1[4], bv1[4];
#pragma unroll
    for (int p = 0; p < 4; ++p) {
      int i = i1 + p * 4 + q;
      int s = srcp[i], d = dstp[i];
      av1[p] = *reinterpret_cast<const ushort4*>(&fni[(size_t)s * HD + h * 64 + 4 * n]);
      bv1[p] = *reinterpret_cast<const ushort4*>(&fnj[(size_t)d * HD + h * 64 + 4 * n]);
    }
    // ---- tile 0: commit to wave-private LDS, MFMA, epilogue
    COMMIT(av0, bv0);
    TILEMMA(a00, a01, i0);
    // ---- tile 1 (same LDS slice, wave-private reuse)
    COMMIT(av1, bv1);
    TILEMMA(a10, a11, i1);
  }
#undef COMMIT
#undef TILEMMA
}

// ---------------- FUSED aggregation + MLP + residual (R9 structure, used L1).
__global__ __launch_bounds__(256) void k_agg_mlp(
    const int* __restrict__ rowptr, const int* __restrict__ srcp,
    const float* __restrict__ elog, const u16* __restrict__ hn,
    const float* __restrict__ Wm, const float* __restrict__ bm,
    float* __restrict__ feat, float* __restrict__ out, int outoff) {
  __shared__ float as_[16 * HD];     // 16 KB: 16 nodes x 256
  int j = threadIdx.x & 63;
  int wid = threadIdx.x >> 6;        // 0..3
  int half = j >> 5;                 // which edge of a pair this lane serves
  int lo = j & 31;                   // col-chunk: cols 8*lo..8*lo+7
  int hA = (j >> 3) & 3;             // head of this lane's columns
  int u = (j & 7) + 8 * half;        // strided index 0..15 within head group
  const float* er = elog + (size_t)hA * NE;
  int n0 = blockIdx.x * 16;
  // ---- phase 1: aggregate 4 consecutive nodes per wave into LDS
#pragma unroll 1
  for (int t4 = 0; t4 < 4; ++t4) {
    int n = n0 + wid * 4 + t4;
    int s0 = rowptr[n], s1 = rowptr[n + 1];
    float m = -1e30f;
    for (int i = s0 + u; i < s1; i += 16) m = fmaxf(m, er[i]);
    m = fmaxf(m, __shfl_xor(m, 1));
    m = fmaxf(m, __shfl_xor(m, 2));
    m = fmaxf(m, __shfl_xor(m, 4));
    m = fmaxf(m, __shfl_xor(m, 32));
    float z = 0.f;
    for (int i = s0 + u; i < s1; i += 16) z += __expf(er[i] - m);
    z += __shfl_xor(z, 1);
    z += __shfl_xor(z, 2);
    z += __shfl_xor(z, 4);
    z += __shfl_xor(z, 32);
    float invz = (z > 0.f) ? 1.0f / z : 0.f;
    float a8[8] = {0.f, 0.f, 0.f, 0.f, 0.f, 0.f, 0.f, 0.f};
    int i = s0;
    for (; i + 8 <= s1; i += 8) {
      int sv[8]; float wv[8];
#pragma unroll
      for (int t = 0; t < 8; ++t) sv[t] = srcp[i + t];
#pragma unroll
      for (int t = 0; t < 8; ++t) wv[t] = __expf(er[i + t] - m) * invz;
      u16x8 vv[4];
#pragma unroll
      for (int g = 0; g < 4; ++g)
        vv[g] = *reinterpret_cast<const u16x8*>(&hn[(size_t)sv[2 * g + half] * HD + 8 * lo]);
#pragma unroll
      for (int g = 0; g < 4; ++g) {
        float w = wv[2 * g + half];
#pragma unroll
        for (int e = 0; e < 8; ++e) a8[e] += b2f(vv[g][e]) * w;
      }
    }
    for (; i + 2 <= s1; i += 2) {
      int s = srcp[i + half];
      float w = __expf(er[i + half] - m) * invz;
      u16x8 v = *reinterpret_cast<const u16x8*>(&hn[(size_t)s * HD + 8 * lo]);
#pragma unroll
      for (int e = 0; e < 8; ++e) a8[e] += b2f(v[e]) * w;
    }
    if (i < s1) {
      int s = srcp[i];
      float w = half ? 0.f : (__expf(er[i] - m) * invz);
      u16x8 v = *reinterpret_cast<const u16x8*>(&hn[(size_t)s * HD + 8 * lo]);
#pragma unroll
      for (int e = 0; e < 8; ++e) a8[e] += b2f(v[e]) * w;
    }
#pragma unroll
    for (int e = 0; e < 8; ++e) a8[e] += __shfl_xor(a8[e], 32);
    if (j < 32) {
      int row = wid * 4 + t4;
      float4 o0, o1;
      o0.x = a8[0]; o0.y = a8[1]; o0.z = a8[2]; o0.w = a8[3];
      o1.x = a8[4]; o1.y = a8[5]; o1.z = a8[6]; o1.w = a8[7];
      *reinterpret_cast<float4*>(&as_[row * HD + 8 * lo]) = o0;
      *reinterpret_cast<float4*>(&as_[row * HD + 8 * lo + 4]) = o1;
    }
  }
  __syncthreads();
  // ---- phase 2: MLP + residual from LDS
  int c = threadIdx.x & 63;
  int g = threadIdx.x >> 6;
  float acc[4] = {0.f, 0.f, 0.f, 0.f};
  for (int k = 0; k < HD; ++k) {
    float wv = Wm[k * HID + c];
#pragma unroll
    for (int t = 0; t < 4; ++t)
      acc[t] += as_[(g * 4 + t) * HD + k] * wv;
  }
  float b = bm[c];
#pragma unroll
  for (int t = 0; t < 4; ++t) {
    int n = n0 + g * 4 + t;
    float v = acc[t] + b + feat[n * HID + c];
    feat[n * HID + c] = v;
    out[n * OUTW + outoff + c] = v;
  }
}

// ---------------- FUSED aggregation + MLP + residual + NEXT-LAYER node proj.
// Same as k_agg_mlp, plus: new feat rows are kept in LDS and projected to
// L1's fni/fnj/hn (8-node/24-acc proven loop x2). hn double-buffered
// (gathers hn_in = L0 values; writes hn_out = L1 values) to avoid the race.
__global__ __launch_bounds__(256) void k_agg_mlp_proj(
    const int* __restrict__ rowptr, const int* __restrict__ srcp,
    const float* __restrict__ elog, const u16* __restrict__ hn_in,
    const float* __restrict__ Wm, const float* __restrict__ bm,
    float* __restrict__ feat, float* __restrict__ out, int outoff,
    const float* __restrict__ Wni, const float* __restrict__ Wnj,
    const float* __restrict__ Wnd, const float* __restrict__ batt,
    u16* __restrict__ fni, u16* __restrict__ fnj, u16* __restrict__ hn_out) {
  __shared__ float as_[16 * HD];     // 16 KB
  __shared__ float fs[16 * HID];     // 4 KB: new feat rows
  int j = threadIdx.x & 63;
  int wid = threadIdx.x >> 6;
  int half = j >> 5;
  int lo = j & 31;
  int hA = (j >> 3) & 3;
  int u = (j & 7) + 8 * half;
  const float* er = elog + (size_t)hA * NE;
  int n0 = blockIdx.x * 16;
  // ---- phase 1: aggregate 4 consecutive nodes per wave into LDS
#pragma unroll 1
  for (int t4 = 0; t4 < 4; ++t4) {
    int n = n0 + wid * 4 + t4;
    int s0 = rowptr[n], s1 = rowptr[n + 1];
    float m = -1e30f;
    for (int i = s0 + u; i < s1; i += 16) m = fmaxf(m, er[i]);
    m = fmaxf(m, __shfl_xor(m, 1));
    m = fmaxf(m, __shfl_xor(m, 2));
    m = fmaxf(m, __shfl_xor(m, 4));
    m = fmaxf(m, __shfl_xor(m, 32));
    float z = 0.f;
    for (int i = s0 + u; i < s1; i += 16) z += __expf(er[i] - m);
    z += __shfl_xor(z, 1);
    z += __shfl_xor(z, 2);
    z += __shfl_xor(z, 4);
    z += __shfl_xor(z, 32);
    float invz = (z > 0.f) ? 1.0f / z : 0.f;
    float a8[8] = {0.f, 0.f, 0.f, 0.f, 0.f, 0.f, 0.f, 0.f};
    int i = s0;
    for (; i + 8 <= s1; i += 8) {
      int sv[8]; float wv[8];
#pragma unroll
      for (int t = 0; t < 8; ++t) sv[t] = srcp[i + t];
#pragma unroll
      for (int t = 0; t < 8; ++t) wv[t] = __expf(er[i + t] - m) * invz;
      u16x8 vv[4];
#pragma unroll
      for (int g = 0; g < 4; ++g)
        vv[g] = *reinterpret_cast<const u16x8*>(&hn_in[(size_t)sv[2 * g + half] * HD + 8 * lo]);
#pragma unroll
      for (int g = 0; g < 4; ++g) {
        float w = wv[2 * g + half];
#pragma unroll
        for (int e = 0; e < 8; ++e) a8[e] += b2f(vv[g][e]) * w;
      }
    }
    for (; i + 2 <= s1; i += 2) {
      int s = srcp[i + half];
      float w = __expf(er[i + half] - m) * invz;
      u16x8 v = *reinterpret_cast<const u16x8*>(&hn_in[(size_t)s * HD + 8 * lo]);
#pragma unroll
      for (int e = 0; e < 8; ++e) a8[e] += b2f(v[e]) * w;
    }
    if (i < s1) {
      int s = srcp[i];
      float w = half ? 0.f : (__expf(er[i] - m) * invz);
      u16x8 v = *reinterpret_cast<const u16x8*>(&hn_in[(size_t)s * HD + 8 * lo]);
#pragma unroll
      for (int e = 0; e < 8; ++e) a8[e] += b2f(v[e]) * w;
    }
#pragma unroll
    for (int e = 0; e < 8; ++e) a8[e] += __shfl_xor(a8[e], 32);
    if (j < 32) {
      int row = wid * 4 + t4;
      float4 o0, o1;
      o0.x = a8[0]; o0.y = a8[1]; o0.z = a8[2]; o0.w = a8[3];
      o1.x = a8[4]; o1.y = a8[5]; o1.z = a8[6]; o1.w = a8[7];
      *reinterpret_cast<float4*>(&as_[row * HD + 8 * lo]) = o0;
      *reinterpret_cast<float4*>(&as_[row * HD + 8 * lo + 4]) = o1;
    }
  }
  __syncthreads();
  // ---- phase 2: MLP + residual from LDS; keep new feat in LDS
  {
    int c = threadIdx.x & 63;
    int g = threadIdx.x >> 6;
    float acc[4] = {0.f, 0.f, 0.f, 0.f};
    for (int k = 0; k < HD; ++k) {
      float wv = Wm[k * HID + c];
#pragma unroll
      for (int t = 0; t < 4; ++t)
        acc[t] += as_[(g * 4 + t) * HD + k] * wv;
    }
    float b = bm[c];
#pragma unroll
    for (int t = 0; t < 4; ++t) {
      int r = g * 4 + t;
      int n = n0 + r;
      float v = acc[t] + b + feat[n * HID + c];
      feat[n * HID + c] = v;
      fs[r * HID + c] = v;
      out[(size_t)n * OUTW + outoff + c] = v;
    }
  }
  __syncthreads();
  // ---- phase 3: project new feat -> next layer's fni/fnj/hn
  int cc = threadIdx.x;
  float b2 = batt[cc];
#pragma unroll 1
  for (int h8 = 0; h8 < 2; ++h8) {
    float aI[8] = {0}, aJ[8] = {0}, aN[8] = {0};
    for (int k = 0; k < HID; ++k) {
      float wi = Wni[k * HD + cc], wj = Wnj[k * HD + cc], wn = Wnd[k * HD + cc];
#pragma unroll
      for (int t = 0; t < 8; ++t) {
        float x = fs[(h8 * 8 + t) * HID + k];
        aI[t] += x * wi; aJ[t] += x * wj; aN[t] += x * wn;
      }
    }
#pragma unroll
    for (int t = 0; t < 8; ++t) {
      int n = n0 + h8 * 8 + t;
      fni[(size_t)n * HD + cc] = f2b(aI[t] + b2);
      fnj[(size_t)n * HD + cc] = f2b(aJ[t]);
      hn_out[(size_t)n * HD + cc] = f2b(aN[t]);
    }
  }
}

extern "C" void kernel_launch(void* const* d_in, const int* in_sizes, int n_in,
                              void* d_out, int out_size, void* d_ws, size_t ws_size,
                              hipStream_t stream) {
  const float* node_feat = (const float*)d_in[0];
  const float* edge_feat = (const float*)d_in[1];
  const int*   src       = (const int*)d_in[2];
  const int*   dst       = (const int*)d_in[3];
  const float* W_embed   = (const float*)d_in[4];
  const float* b_embed   = (const float*)d_in[5];
  const float* W_ni      = (const float*)d_in[6];
  const float* W_nj      = (const float*)d_in[7];
  const float* W_fij     = (const float*)d_in[8];
  const float* b_att     = (const float*)d_in[9];
  const float* attn      = (const float*)d_in[10];
  const float* W_node    = (const float*)d_in[11];
  const float* W_mlp     = (const float*)d_in[12];
  const float* b_mlp     = (const float*)d_in[13];
  float* out = (float*)d_out;

  // workspace layout
  float* ws   = (float*)d_ws;
  float* feat = ws;                                   // NN*HID f32
  u16*  fni   = (u16*)(feat + (size_t)NN * HID);      // NN*HD bf16
  u16*  fnj   = fni + (size_t)NN * HD;                // NN*HD bf16
  u16*  hnA   = fnj + (size_t)NN * HD;                // NN*HD bf16 (L0)
  u16*  hnB   = hnA + (size_t)NN * HD;                // NN*HD bf16 (L1)
  u16*  efbp  = hnB + (size_t)NN * HD;                // NE*HID bf16 (CSR slot order)
  u16*  Wt0   = efbp + (size_t)NE * HID;              // HD*HID bf16
  u16*  Wt1   = Wt0 + (size_t)HD * HID;               // HD*HID bf16
  float* elog = (float*)(Wt1 + (size_t)HD * HID);     // HEADS*NE f32 (head-major)
  int* counts = (int*)(elog + (size_t)NE * HEADS);    // NN
  int* rowptr = counts + NN;                          // NN+1
  int* cursor = rowptr + NN + 1;                      // NN
  int* srcp   = cursor + NN;                          // NE
  int* dstp   = srcp + NE;                            // NE
  int* pos_of = dstp + NE;                            // NE

  hipMemsetAsync(counts, 0, sizeof(int) * NN, stream);

  // fused embed + edge-count + L0 nodeproj
  k_embed_count_proj<<<NN / 16 + NE / 256, 256, 0, stream>>>(
      node_feat, W_embed, b_embed, W_ni, W_nj, W_node, b_att,
      feat, out, dst, counts, fni, fnj, hnA);
  k_scan<<<1, 1024, 0, stream>>>(counts, rowptr, cursor);
  k_scatter<<<NE / 256, 256, 0, stream>>>(dst, src, rowptr, cursor, srcp, dstp, pos_of);
  k_permute_prepw<<<(NE * 16) / 256 + 128, 256, 0, stream>>>(
      edge_feat, pos_of, efbp, W_fij, Wt0, Wt1);

  // ---- layer 0
  k_edgelogits<<<2048, 256, 0, stream>>>(efbp, srcp, dstp, fni, fnj, Wt0,
                                         attn, elog);
  k_agg_mlp_proj<<<NN / 16, 256, 0, stream>>>(
      rowptr, srcp, elog, hnA, W_mlp, b_mlp, feat, out, 80,
      W_ni + (size_t)HID * HD, W_nj + (size_t)HID * HD, W_node + (size_t)HID * HD,
      b_att + HD, fni, fnj, hnB);

  // ---- layer 1
  k_edgelogits<<<2048, 256, 0, stream>>>(efbp, srcp, dstp, fni, fnj, Wt1,
                                         attn + HEADS * HID, elog);
  k_agg_mlp<<<NN / 16, 256, 0, stream>>>(rowptr, srcp, elog, hnB,
                                         W_mlp + (size_t)HD * HID, b_mlp + HID,
                                         feat, out, 144);
}

// Round 12
// 445.132 us; speedup vs baseline: 1.0917x; 1.0494x over previous
//
#include <hip/hip_runtime.h>
#include <math.h>

#define NN 20000
#define NE 320000
#define IN_DIM 16
#define HID 64
#define HEADS 4
#define HD 256          // HEADS*HID
#define OUTW 208        // 16 + 3*64
#define NEG 0.2f

typedef unsigned short u16;
typedef unsigned int u32;
typedef __attribute__((ext_vector_type(8))) short bf16x8;   // MFMA A/B frag
typedef __attribute__((ext_vector_type(8))) unsigned short u16x8;
typedef __attribute__((ext_vector_type(4))) float f32x4;    // MFMA C/D frag
typedef __attribute__((ext_vector_type(2))) float f32x2;    // packed-FMA pair

__device__ __forceinline__ float b2f(u16 u) {
  union { u32 i; float f; } c; c.i = ((u32)u) << 16; return c.f;
}
__device__ __forceinline__ float u2f(u32 x) {
  union { u32 i; float f; } c; c.i = x; return c.f;
}
__device__ __forceinline__ u16 f2b(float f) {
  union { float f; u32 i; } c; c.f = f;
  u32 r = (c.i + 0x7FFFu + ((c.i >> 16) & 1u)) >> 16;
  return (u16)r;
}

// ---------------- FUSED embed + L0 node projections (+ edge-count tail).
__global__ __launch_bounds__(256) void k_embed_count_proj(
    const float* __restrict__ nf, const float* __restrict__ We,
    const float* __restrict__ be, const float* __restrict__ Wni,
    const float* __restrict__ Wnj, const float* __restrict__ Wnd,
    const float* __restrict__ batt, float* __restrict__ feat,
    float* __restrict__ out, const int* __restrict__ dst,
    int* __restrict__ counts, u16* __restrict__ fni,
    u16* __restrict__ fnj, u16* __restrict__ hn) {
  int bid = blockIdx.x;
  const int EB = NN / 16;  // 1250
  if (bid < EB) {
    __shared__ float fs[16 * HID];   // 4 KB
    int n0 = bid * 16;
    int c = threadIdx.x & 63;
    int g = threadIdx.x >> 6;        // 0..3, each group embeds 4 nodes
#pragma unroll
    for (int t = 0; t < 4; ++t) {
      int r = g * 4 + t;
      int n = n0 + r;
      float acc = be[c];
#pragma unroll
      for (int k = 0; k < IN_DIM; ++k)
        acc += nf[n * IN_DIM + k] * We[k * HID + c];
      fs[r * HID + c] = acc;
      feat[(size_t)n * HID + c] = acc;
      out[(size_t)n * OUTW + 16 + c] = acc;
      if (c < IN_DIM) out[(size_t)n * OUTW + c] = nf[n * IN_DIM + c];
    }
    __syncthreads();
    int cc = threadIdx.x;            // 0..255: output column in HD
    float b = batt[cc];
#pragma unroll 1
    for (int h8 = 0; h8 < 2; ++h8) {
      float aI[8] = {0}, aJ[8] = {0}, aN[8] = {0};
      for (int k = 0; k < HID; ++k) {
        float wi = Wni[k * HD + cc], wj = Wnj[k * HD + cc], wn = Wnd[k * HD + cc];
#pragma unroll
        for (int t = 0; t < 8; ++t) {
          float x = fs[(h8 * 8 + t) * HID + k];
          aI[t] += x * wi; aJ[t] += x * wj; aN[t] += x * wn;
        }
      }
#pragma unroll
      for (int t = 0; t < 8; ++t) {
        int n = n0 + h8 * 8 + t;
        fni[(size_t)n * HD + cc] = f2b(aI[t] + b);
        fnj[(size_t)n * HD + cc] = f2b(aJ[t]);
        hn[(size_t)n * HD + cc]  = f2b(aN[t]);
      }
    }
  } else {
    int e = (bid - EB) * 256 + threadIdx.x;
    if (e < NE) atomicAdd(&counts[dst[e]], 1);
  }
}

// single block, 1024 threads, SINGLE-PASS scan (+ fused cursor zeroing)
__global__ void k_scan(const int* __restrict__ counts, int* __restrict__ rowptr,
                       int* __restrict__ cursor) {
  __shared__ int wsum[16];
  const int PT = 20;                // 1000 active threads * 20 = 20000
  int t = threadIdx.x;
  int lane = t & 63, wid = t >> 6;
  int base = t * PT;
  int c[PT];
  int tot = 0;
  if (t < 1000) {
#pragma unroll
    for (int i = 0; i < PT; ++i) {
      int v = counts[base + i];
      cursor[base + i] = 0;
      tot += v;
      c[i] = tot;                   // inclusive thread-local prefix
    }
  }
  int x = tot;
#pragma unroll
  for (int d = 1; d < 64; d <<= 1) {
    int y = __shfl_up(x, d);
    if (lane >= d) x += y;
  }
  int lexcl = x - tot;              // exclusive within wave
  if (lane == 63) wsum[wid] = x;
  __syncthreads();
  if (wid == 0) {
    int wv = (lane < 16) ? wsum[lane] : 0;
#pragma unroll
    for (int d = 1; d < 16; d <<= 1) {
      int y = __shfl_up(wv, d);
      if (lane >= d) wv += y;
    }
    if (lane < 16) wsum[lane] = wv; // inclusive wave sums
  }
  __syncthreads();
  int woff = (wid == 0) ? 0 : wsum[wid - 1];
  int offset = woff + lexcl;
  if (t == 0) rowptr[0] = 0;
  if (t < 1000) {
#pragma unroll
    for (int i = 0; i < PT; ++i) rowptr[base + i + 1] = offset + c[i];
  }
}

// scatter: src/dst permuted into CSR order + pos_of (edge -> CSR slot)
__global__ void k_scatter(const int* __restrict__ dst, const int* __restrict__ src,
                          const int* __restrict__ rowptr, int* __restrict__ cursor,
                          int* __restrict__ srcp, int* __restrict__ dstp,
                          int* __restrict__ pos_of) {
  int e = blockIdx.x * blockDim.x + threadIdx.x;
  if (e >= NE) return;
  int d = dst[e];
  int pos = rowptr[d] + atomicAdd(&cursor[d], 1);
  srcp[pos] = src[e];
  dstp[pos] = d;
  pos_of[e] = pos;
}

// ---------------- SCATTER-permute+convert edge_feat into CSR slot order (bf16).
__global__ void k_permute_prepw(const float* __restrict__ ef, const int* __restrict__ pos_of,
                                u16* __restrict__ efbp, const float* __restrict__ Wf,
                                u16* __restrict__ Wt0, u16* __restrict__ Wt1) {
  int bid = blockIdx.x;
  const int PB = (NE * 16) / 256;  // 20000
  if (bid < PB) {
    int t = bid * 256 + threadIdx.x;
    int e = t >> 4, c = (t & 15) * 4;
    int slot = pos_of[e];                             // coalesced/broadcast read
    float4 v = *reinterpret_cast<const float4*>(&ef[(size_t)e * HID + c]);  // streaming
    ushort4 o;
    o.x = f2b(v.x); o.y = f2b(v.y); o.z = f2b(v.z); o.w = f2b(v.w);
    *reinterpret_cast<ushort4*>(&efbp[(size_t)slot * HID + c]) = o;        // scatter row
  } else {
    int r = (bid - PB) * 256 + threadIdx.x;   // 0..32767 over 128 blocks
    int Lw = r >> 14;                          // 16384 entries per layer
    int idx = r & 16383;
    int nn2 = idx >> 6, kk2 = idx & 63;
    u16* WtL = Lw ? Wt1 : Wt0;
    WtL[nn2 * HID + kk2] = f2b(Wf[(size_t)Lw * HID * HD + kk2 * HD + nn2]);
  }
}

// ---------------- edge logits via MFMA over CSR slots, 2-tile ILP.
// R7 structure: XCD-aware block swizzle + ADJACENT-pair tiles; ushort4
// gathers; conflict-free LDS commit [p*4+q][4*n]. elog[h*NE + slot].
__global__ __launch_bounds__(256) void k_edgelogits(
    const u16* __restrict__ efbp, const int* __restrict__ srcp,
    const int* __restrict__ dstp, const u16* __restrict__ fni,
    const u16* __restrict__ fnj, const u16* __restrict__ Wt,
    const float* __restrict__ attnL, float* __restrict__ elog) {
  __shared__ float gb[HEADS][16][68];   // per-wave slice, +4 pad
  int h = threadIdx.x >> 6;            // wave = head
  int l = threadIdx.x & 63;
  int q = l >> 4;                      // quad
  int n = l & 15;
  bf16x8 bfr[4][2];
#pragma unroll
  for (int nt = 0; nt < 4; ++nt)
#pragma unroll
    for (int kk = 0; kk < 2; ++kk)
      bfr[nt][kk] = *reinterpret_cast<const bf16x8*>(
          &Wt[(h * 64 + nt * 16 + n) * HID + kk * 32 + q * 8]);
  float at[4];
#pragma unroll
  for (int nt = 0; nt < 4; ++nt) at[nt] = attnL[h * 64 + nt * 16 + n];

#define COMMIT(av, bv)                                                \
  {                                                                   \
    _Pragma("unroll")                                                 \
    for (int p = 0; p < 4; ++p) {                                     \
      float4 g;                                                       \
      g.x = b2f(av[p].x) + b2f(bv[p].x);                              \
      g.y = b2f(av[p].y) + b2f(bv[p].y);                              \
      g.z = b2f(av[p].z) + b2f(bv[p].z);                              \
      g.w = b2f(av[p].w) + b2f(bv[p].w);                              \
      *reinterpret_cast<float4*>(&gb[h][p * 4 + q][4 * n]) = g;       \
    }                                                                 \
  }

#define TILEMMA(aa0, aa1, ibase)                                                  \
  {                                                                               \
    float sumr[4] = {0.f, 0.f, 0.f, 0.f};                                         \
    _Pragma("unroll")                                                             \
    for (int nt = 0; nt < 4; ++nt) {                                              \
      f32x4 acc = {0.f, 0.f, 0.f, 0.f};                                           \
      acc = __builtin_amdgcn_mfma_f32_16x16x32_bf16(aa0, bfr[nt][0], acc, 0, 0, 0); \
      acc = __builtin_amdgcn_mfma_f32_16x16x32_bf16(aa1, bfr[nt][1], acc, 0, 0, 0); \
      _Pragma("unroll")                                                           \
      for (int r = 0; r < 4; ++r) {                                               \
        float v = acc[r] + gb[h][q * 4 + r][nt * 16 + n];                         \
        v = v > 0.f ? v : NEG * v;                                                \
        sumr[r] += v * at[nt];                                                    \
      }                                                                           \
    }                                                                             \
    _Pragma("unroll")                                                             \
    for (int r = 0; r < 4; ++r) {                                                 \
      float v = sumr[r];                                                          \
      v += __shfl_xor(v, 1);                                                      \
      v += __shfl_xor(v, 2);                                                      \
      v += __shfl_xor(v, 4);                                                      \
      v += __shfl_xor(v, 8);                                                      \
      sumr[r] = v;                                                                \
    }                                                                             \
    if (n == 0) {                                                                 \
      float4 o_;                                                                  \
      o_.x = sumr[0]; o_.y = sumr[1]; o_.z = sumr[2]; o_.w = sumr[3];             \
      *reinterpret_cast<float4*>(&elog[(size_t)h * NE + (ibase) + q * 4]) = o_;   \
    }                                                                             \
  }

  const int NT2 = NE / 32;  // 10000 pair-groups
  const int G = gridDim.x;  // 2048 (multiple of 8)
  int swz = (blockIdx.x & 7) * (G >> 3) + (blockIdx.x >> 3);  // XCD-contiguous
  for (int pg = swz; pg < NT2; pg += G) {
    int i0 = pg * 32;        // tiles 2pg and 2pg+1: adjacent 16-edge groups
    int i1 = i0 + 16;
    bf16x8 a00 = *reinterpret_cast<const bf16x8*>(&efbp[(size_t)(i0 + n) * HID + q * 8]);
    bf16x8 a01 = *reinterpret_cast<const bf16x8*>(&efbp[(size_t)(i0 + n) * HID + 32 + q * 8]);
    ushort4 av0[4], bv0[4];
#pragma unroll
    for (int p = 0; p < 4; ++p) {
      int i = i0 + p * 4 + q;
      int s = srcp[i], d = dstp[i];
      av0[p] = *reinterpret_cast<const ushort4*>(&fni[(size_t)s * HD + h * 64 + 4 * n]);
      bv0[p] = *reinterpret_cast<const ushort4*>(&fnj[(size_t)d * HD + h * 64 + 4 * n]);
    }
    bf16x8 a10 = *reinterpret_cast<const bf16x8*>(&efbp[(size_t)(i1 + n) * HID + q * 8]);
    bf16x8 a11 = *reinterpret_cast<const bf16x8*>(&efbp[(size_t)(i1 + n) * HID + 32 + q * 8]);
    ushort4 av1[4], bv1[4];
#pragma unroll
    for (int p = 0; p < 4; ++p) {
      int i = i1 + p * 4 + q;
      int s = srcp[i], d = dstp[i];
      av1[p] = *reinterpret_cast<const ushort4*>(&fni[(size_t)s * HD + h * 64 + 4 * n]);
      bv1[p] = *reinterpret_cast<const ushort4*>(&fnj[(size_t)d * HD + h * 64 + 4 * n]);
    }
    COMMIT(av0, bv0);
    TILEMMA(a00, a01, i0);
    COMMIT(av1, bv1);
    TILEMMA(a10, a11, i1);
  }
#undef COMMIT
#undef TILEMMA
}

// ======== shared agg phase-1 body (used by both agg kernels) ========
// Per wave, 4 consecutive nodes. Single max pass; z FOLDED into the weighted
// pass (unnormalized weights, one invz scale at the end); only the 4 weights
// each lane actually uses are computed (4 exps, not 8); f32x2 packed FMA.
#define AGG_NODE_BODY(HNBUF)                                                      \
    int s0 = rowptr[n], s1 = rowptr[n + 1];                                       \
    float m = -1e30f;                                                             \
    for (int i = s0 + u; i < s1; i += 16) m = fmaxf(m, er[i]);                    \
    m = fmaxf(m, __shfl_xor(m, 1));                                               \
    m = fmaxf(m, __shfl_xor(m, 2));                                               \
    m = fmaxf(m, __shfl_xor(m, 4));                                               \
    m = fmaxf(m, __shfl_xor(m, 32));                                              \
    f32x2 a2[4];                                                                  \
    a2[0] = 0.f; a2[1] = 0.f; a2[2] = 0.f; a2[3] = 0.f;                           \
    float zl = 0.f;                                                               \
    int i = s0;                                                                   \
    for (; i + 8 <= s1; i += 8) {                                                 \
      int sv[4]; float wv[4];                                                     \
      _Pragma("unroll")                                                           \
      for (int g = 0; g < 4; ++g) sv[g] = srcp[i + 2 * g + half];                 \
      _Pragma("unroll")                                                           \
      for (int g = 0; g < 4; ++g) wv[g] = __expf(er[i + 2 * g + half] - m);       \
      union { u16x8 v; u32 w[4]; } cv[4];                                         \
      _Pragma("unroll")                                                           \
      for (int g = 0; g < 4; ++g)                                                 \
        cv[g].v = *reinterpret_cast<const u16x8*>(&HNBUF[(size_t)sv[g] * HD + 8 * lo]); \
      _Pragma("unroll")                                                           \
      for (int g = 0; g < 4; ++g) {                                               \
        float w = wv[g];                                                          \
        zl += w;                                                                  \
        _Pragma("unroll")                                                         \
        for (int k = 0; k < 4; ++k) {                                             \
          u32 b_ = cv[g].w[k];                                                    \
          f32x2 x;                                                                \
          x[0] = u2f(b_ << 16);                                                   \
          x[1] = u2f(b_ & 0xFFFF0000u);                                           \
          a2[k] += x * w;                                                         \
        }                                                                         \
      }                                                                           \
    }                                                                             \
    for (; i + 2 <= s1; i += 2) {                                                 \
      int s = srcp[i + half];                                                     \
      float w = __expf(er[i + half] - m);                                         \
      zl += w;                                                                    \
      union { u16x8 v; u32 w[4]; } cv;                                            \
      cv.v = *reinterpret_cast<const u16x8*>(&HNBUF[(size_t)s * HD + 8 * lo]);    \
      _Pragma("unroll")                                                           \
      for (int k = 0; k < 4; ++k) {                                               \
        u32 b_ = cv.w[k];                                                         \
        f32x2 x;                                                                  \
        x[0] = u2f(b_ << 16);                                                     \
        x[1] = u2f(b_ & 0xFFFF0000u);                                             \
        a2[k] += x * w;                                                           \
      }                                                                           \
    }                                                                             \
    if (i < s1) {                                                                 \
      int s = srcp[i];                                                            \
      float w = half ? 0.f : __expf(er[i] - m);                                   \
      zl += w;                                                                    \
      union { u16x8 v; u32 w[4]; } cv;                                            \
      cv.v = *reinterpret_cast<const u16x8*>(&HNBUF[(size_t)s * HD + 8 * lo]);    \
      _Pragma("unroll")                                                           \
      for (int k = 0; k < 4; ++k) {                                               \
        u32 b_ = cv.w[k];                                                         \
        f32x2 x;                                                                  \
        x[0] = u2f(b_ << 16);                                                     \
        x[1] = u2f(b_ & 0xFFFF0000u);                                             \
        a2[k] += x * w;                                                           \
      }                                                                           \
    }                                                                             \
    _Pragma("unroll")                                                             \
    for (int k = 0; k < 4; ++k) {                                                 \
      a2[k][0] += __shfl_xor(a2[k][0], 32);                                       \
      a2[k][1] += __shfl_xor(a2[k][1], 32);                                       \
    }                                                                             \
    zl += __shfl_xor(zl, 32);                                                     \
    float invz = (zl > 0.f) ? 1.0f / zl : 0.f;                                    \
    _Pragma("unroll")                                                             \
    for (int k = 0; k < 4; ++k) a2[k] *= invz;                                    \
    if (j < 32) {                                                                 \
      int row = wid * 4 + t4;                                                     \
      float4 o0, o1;                                                              \
      o0.x = a2[0][0]; o0.y = a2[0][1]; o0.z = a2[1][0]; o0.w = a2[1][1];         \
      o1.x = a2[2][0]; o1.y = a2[2][1]; o1.z = a2[3][0]; o1.w = a2[3][1];         \
      *reinterpret_cast<float4*>(&as_[row * HD + 8 * lo]) = o0;                   \
      *reinterpret_cast<float4*>(&as_[row * HD + 8 * lo + 4]) = o1;               \
    }

// ---------------- FUSED aggregation + MLP + residual (L1).
__global__ __launch_bounds__(256) void k_agg_mlp(
    const int* __restrict__ rowptr, const int* __restrict__ srcp,
    const float* __restrict__ elog, const u16* __restrict__ hn,
    const float* __restrict__ Wm, const float* __restrict__ bm,
    float* __restrict__ feat, float* __restrict__ out, int outoff) {
  __shared__ float as_[16 * HD];     // 16 KB: 16 nodes x 256
  int j = threadIdx.x & 63;
  int wid = threadIdx.x >> 6;        // 0..3
  int half = j >> 5;
  int lo = j & 31;
  int hA = (j >> 3) & 3;
  int u = (j & 7) + 8 * half;
  const float* er = elog + (size_t)hA * NE;
  int n0 = blockIdx.x * 16;
#pragma unroll 1
  for (int t4 = 0; t4 < 4; ++t4) {
    int n = n0 + wid * 4 + t4;
    AGG_NODE_BODY(hn)
  }
  __syncthreads();
  // ---- phase 2: MLP + residual from LDS
  int c = threadIdx.x & 63;
  int g = threadIdx.x >> 6;
  float acc[4] = {0.f, 0.f, 0.f, 0.f};
  for (int k = 0; k < HD; ++k) {
    float wv = Wm[k * HID + c];
#pragma unroll
    for (int t = 0; t < 4; ++t)
      acc[t] += as_[(g * 4 + t) * HD + k] * wv;
  }
  float b = bm[c];
#pragma unroll
  for (int t = 0; t < 4; ++t) {
    int n = n0 + g * 4 + t;
    float v = acc[t] + b + feat[n * HID + c];
    feat[n * HID + c] = v;
    out[n * OUTW + outoff + c] = v;
  }
}

// ---------------- FUSED aggregation + MLP + residual + NEXT-LAYER node proj.
// hn double-buffered (gathers hn_in = L0; writes hn_out = L1).
__global__ __launch_bounds__(256) void k_agg_mlp_proj(
    const int* __restrict__ rowptr, const int* __restrict__ srcp,
    const float* __restrict__ elog, const u16* __restrict__ hn_in,
    const float* __restrict__ Wm, const float* __restrict__ bm,
    float* __restrict__ feat, float* __restrict__ out, int outoff,
    const float* __restrict__ Wni, const float* __restrict__ Wnj,
    const float* __restrict__ Wnd, const float* __restrict__ batt,
    u16* __restrict__ fni, u16* __restrict__ fnj, u16* __restrict__ hn_out) {
  __shared__ float as_[16 * HD];     // 16 KB
  __shared__ float fs[16 * HID];     // 4 KB: new feat rows
  int j = threadIdx.x & 63;
  int wid = threadIdx.x >> 6;
  int half = j >> 5;
  int lo = j & 31;
  int hA = (j >> 3) & 3;
  int u = (j & 7) + 8 * half;
  const float* er = elog + (size_t)hA * NE;
  int n0 = blockIdx.x * 16;
#pragma unroll 1
  for (int t4 = 0; t4 < 4; ++t4) {
    int n = n0 + wid * 4 + t4;
    AGG_NODE_BODY(hn_in)
  }
  __syncthreads();
  // ---- phase 2: MLP + residual from LDS; keep new feat in LDS
  {
    int c = threadIdx.x & 63;
    int g = threadIdx.x >> 6;
    float acc[4] = {0.f, 0.f, 0.f, 0.f};
    for (int k = 0; k < HD; ++k) {
      float wv = Wm[k * HID + c];
#pragma unroll
      for (int t = 0; t < 4; ++t)
        acc[t] += as_[(g * 4 + t) * HD + k] * wv;
    }
    float b = bm[c];
#pragma unroll
    for (int t = 0; t < 4; ++t) {
      int r = g * 4 + t;
      int n = n0 + r;
      float v = acc[t] + b + feat[n * HID + c];
      feat[n * HID + c] = v;
      fs[r * HID + c] = v;
      out[(size_t)n * OUTW + outoff + c] = v;
    }
  }
  __syncthreads();
  // ---- phase 3: project new feat -> next layer's fni/fnj/hn
  int cc = threadIdx.x;
  float b2 = batt[cc];
#pragma unroll 1
  for (int h8 = 0; h8 < 2; ++h8) {
    float aI[8] = {0}, aJ[8] = {0}, aN[8] = {0};
    for (int k = 0; k < HID; ++k) {
      float wi = Wni[k * HD + cc], wj = Wnj[k * HD + cc], wn = Wnd[k * HD + cc];
#pragma unroll
      for (int t = 0; t < 8; ++t) {
        float x = fs[(h8 * 8 + t) * HID + k];
        aI[t] += x * wi; aJ[t] += x * wj; aN[t] += x * wn;
      }
    }
#pragma unroll
    for (int t = 0; t < 8; ++t) {
      int n = n0 + h8 * 8 + t;
      fni[(size_t)n * HD + cc] = f2b(aI[t] + b2);
      fnj[(size_t)n * HD + cc] = f2b(aJ[t]);
      hn_out[(size_t)n * HD + cc] = f2b(aN[t]);
    }
  }
}

extern "C" void kernel_launch(void* const* d_in, const int* in_sizes, int n_in,
                              void* d_out, int out_size, void* d_ws, size_t ws_size,
                              hipStream_t stream) {
  const float* node_feat = (const float*)d_in[0];
  const float* edge_feat = (const float*)d_in[1];
  const int*   src       = (const int*)d_in[2];
  const int*   dst       = (const int*)d_in[3];
  const float* W_embed   = (const float*)d_in[4];
  const float* b_embed   = (const float*)d_in[5];
  const float* W_ni      = (const float*)d_in[6];
  const float* W_nj      = (const float*)d_in[7];
  const float* W_fij     = (const float*)d_in[8];
  const float* b_att     = (const float*)d_in[9];
  const float* attn      = (const float*)d_in[10];
  const float* W_node    = (const float*)d_in[11];
  const float* W_mlp     = (const float*)d_in[12];
  const float* b_mlp     = (const float*)d_in[13];
  float* out = (float*)d_out;

  // workspace layout
  float* ws   = (float*)d_ws;
  float* feat = ws;                                   // NN*HID f32
  u16*  fni   = (u16*)(feat + (size_t)NN * HID);      // NN*HD bf16
  u16*  fnj   = fni + (size_t)NN * HD;                // NN*HD bf16
  u16*  hnA   = fnj + (size_t)NN * HD;                // NN*HD bf16 (L0)
  u16*  hnB   = hnA + (size_t)NN * HD;                // NN*HD bf16 (L1)
  u16*  efbp  = hnB + (size_t)NN * HD;                // NE*HID bf16 (CSR slot order)
  u16*  Wt0   = efbp + (size_t)NE * HID;              // HD*HID bf16
  u16*  Wt1   = Wt0 + (size_t)HD * HID;               // HD*HID bf16
  float* elog = (float*)(Wt1 + (size_t)HD * HID);     // HEADS*NE f32 (head-major)
  int* counts = (int*)(elog + (size_t)NE * HEADS);    // NN
  int* rowptr = counts + NN;                          // NN+1
  int* cursor = rowptr + NN + 1;                      // NN
  int* srcp   = cursor + NN;                          // NE
  int* dstp   = srcp + NE;                            // NE
  int* pos_of = dstp + NE;                            // NE

  hipMemsetAsync(counts, 0, sizeof(int) * NN, stream);

  // fused embed + edge-count + L0 nodeproj
  k_embed_count_proj<<<NN / 16 + NE / 256, 256, 0, stream>>>(
      node_feat, W_embed, b_embed, W_ni, W_nj, W_node, b_att,
      feat, out, dst, counts, fni, fnj, hnA);
  k_scan<<<1, 1024, 0, stream>>>(counts, rowptr, cursor);
  k_scatter<<<NE / 256, 256, 0, stream>>>(dst, src, rowptr, cursor, srcp, dstp, pos_of);
  k_permute_prepw<<<(NE * 16) / 256 + 128, 256, 0, stream>>>(
      edge_feat, pos_of, efbp, W_fij, Wt0, Wt1);

  // ---- layer 0
  k_edgelogits<<<2048, 256, 0, stream>>>(efbp, srcp, dstp, fni, fnj, Wt0,
                                         attn, elog);
  k_agg_mlp_proj<<<NN / 16, 256, 0, stream>>>(
      rowptr, srcp, elog, hnA, W_mlp, b_mlp, feat, out, 80,
      W_ni + (size_t)HID * HD, W_nj + (size_t)HID * HD, W_node + (size_t)HID * HD,
      b_att + HD, fni, fnj, hnB);

  // ---- layer 1
  k_edgelogits<<<2048, 256, 0, stream>>>(efbp, srcp, dstp, fni, fnj, Wt1,
                                         attn + HEADS * HID, elog);
  k_agg_mlp<<<NN / 16, 256, 0, stream>>>(rowptr, srcp, elog, hnB,
                                         W_mlp + (size_t)HD * HID, b_mlp + HID,
                                         feat, out, 144);
}